// Round 1
// baseline (1382.801 us; speedup 1.0000x reference)
//
#include <hip/hip_runtime.h>
#include <hip/hip_bf16.h>

#define NBLK 100
#define DIM 128
#define EVEC (NBLK * DIM)          // 12800 floats per accumulator array
#define SLICE (2 * EVEC + NBLK)    // 25700 floats per workgroup partial slice
#define EPSV 1e-8f

// Kernel 1: single pass over z. Each half-wave (32 lanes) processes one point:
// float4 load per lane (coalesced 1KB per wave iteration), half-wave shuffle
// reduce for ||z||, then LDS atomic accumulation of sums and z/||z|| sums.
// LDS layout uses dim permutation pi(4*hl + k) = hl + 32*k so that the 64
// lanes of a wave hit banks hl%32 -> only the free 2-way aliasing (m136).
// Dot products / norms downstream are permutation-invariant.
__global__ __launch_bounds__(1024) void rbc_accum(
    const float4* __restrict__ z4, const int* __restrict__ ids,
    float* __restrict__ ws, int N, int nwaves) {
  __shared__ float lsum[EVEC];
  __shared__ float lnsum[EVEC];
  __shared__ float lcnt[NBLK];
  const int tid = threadIdx.x;
  for (int e = tid; e < EVEC; e += 1024) { lsum[e] = 0.f; lnsum[e] = 0.f; }
  if (tid < NBLK) lcnt[tid] = 0.f;
  __syncthreads();

  const int lane = tid & 63;
  const int half = lane >> 5;   // which point of the pair
  const int hl   = lane & 31;   // lane within half-wave
  const int w = blockIdx.x * (blockDim.x >> 6) + (tid >> 6);
  const int npairs = (N + 1) >> 1;

  for (int j = w; j < npairs; j += nwaves) {
    const int i = 2 * j + half;
    if (i < N) {
      const int b = ids[i];
      const float4 v = z4[(size_t)i * 32 + hl];
      float sq = v.x * v.x + v.y * v.y + v.z * v.z + v.w * v.w;
      // reduce within the 32-lane half (masks < 32 keep halves separate)
      #pragma unroll
      for (int m = 1; m < 32; m <<= 1) sq += __shfl_xor(sq, m);
      const float rn = 1.0f / fmaxf(sqrtf(sq), EPSV);
      const int base = b * DIM + hl;
      atomicAdd(&lsum[base      ], v.x);
      atomicAdd(&lsum[base + 32 ], v.y);
      atomicAdd(&lsum[base + 64 ], v.z);
      atomicAdd(&lsum[base + 96 ], v.w);
      atomicAdd(&lnsum[base      ], v.x * rn);
      atomicAdd(&lnsum[base + 32 ], v.y * rn);
      atomicAdd(&lnsum[base + 64 ], v.z * rn);
      atomicAdd(&lnsum[base + 96 ], v.w * rn);
      if (hl == 0) atomicAdd(&lcnt[b], 1.0f);
    }
  }
  __syncthreads();

  // Non-atomic flush: each WG writes its whole private slice.
  float* slice = ws + (size_t)blockIdx.x * SLICE;
  for (int e = tid; e < EVEC; e += 1024) {
    slice[e] = lsum[e];
    slice[EVEC + e] = lnsum[e];
  }
  if (tid < NBLK) slice[2 * EVEC + tid] = lcnt[tid];
}

// Kernel 2: reduce G per-WG slices into one final slice.
__global__ void rbc_reduce(const float* __restrict__ ws,
                           float* __restrict__ fin, int G) {
  const int e = blockIdx.x * 256 + threadIdx.x;
  if (e >= SLICE) return;
  float s = 0.f;
  for (int g = 0; g < G; ++g) s += ws[(size_t)g * SLICE + e];
  fin[e] = s;
}

// Kernel 3: per-block mean cosine + final scalar. One wave per block, 8 waves.
__global__ __launch_bounds__(512) void rbc_final(const float* __restrict__ fin,
                                                 float* __restrict__ out) {
  __shared__ float l_tot;
  __shared__ float l_cnt;
  const int tid = threadIdx.x;
  if (tid == 0) { l_tot = 0.f; l_cnt = 0.f; }
  __syncthreads();
  const int wave = tid >> 6, lane = tid & 63;
  for (int b = wave; b < NBLK; b += 8) {
    const float s0 = fin[b * DIM + lane];
    const float s1 = fin[b * DIM + lane + 64];
    const float n0 = fin[EVEC + b * DIM + lane];
    const float n1 = fin[EVEC + b * DIM + lane + 64];
    float S2 = s0 * s0 + s1 * s1;   // ||sums||^2
    float ND = n0 * s0 + n1 * s1;   // nsums . sums
    #pragma unroll
    for (int m = 1; m < 64; m <<= 1) {
      S2 += __shfl_xor(S2, m);
      ND += __shfl_xor(ND, m);
    }
    if (lane == 0) {
      const float cnt  = fin[2 * EVEC + b];
      const float cnt1 = fmaxf(cnt, 1.0f);
      const float cn   = fmaxf(sqrtf(S2) / cnt1, EPSV);  // ||center|| clamped
      const float mean_cos = ND / (cnt1 * cnt1 * cn);
      if (cnt > 1.0f) {
        atomicAdd(&l_tot, 1.0f - mean_cos);
        atomicAdd(&l_cnt, 1.0f);
      }
    }
  }
  __syncthreads();
  if (tid == 0) out[0] = l_tot / fmaxf(l_cnt, 1.0f);
}

extern "C" void kernel_launch(void* const* d_in, const int* in_sizes, int n_in,
                              void* d_out, int out_size, void* d_ws, size_t ws_size,
                              hipStream_t stream) {
  const float* z = (const float*)d_in[0];
  const int* ids = (const int*)d_in[1];
  const int N = in_sizes[1];
  float* out = (float*)d_out;
  float* ws = (float*)d_ws;

  // G workgroup slices + 1 final slice must fit in ws.
  size_t cap = ws_size / (sizeof(float) * (size_t)SLICE);
  int G = 256;
  if (cap < (size_t)G + 1) G = (int)(cap > 1 ? cap - 1 : 1);

  const int waves_per_block = 1024 / 64;
  const int nwaves = G * waves_per_block;

  rbc_accum<<<G, 1024, 0, stream>>>((const float4*)z, ids, ws, N, nwaves);

  float* fin = ws + (size_t)G * SLICE;
  rbc_reduce<<<(SLICE + 255) / 256, 256, 0, stream>>>(ws, fin, G);
  rbc_final<<<1, 512, 0, stream>>>(fin, out);
}

// Round 2
// 123.594 us; speedup vs baseline: 11.1882x; 11.1882x over previous
//
#include <hip/hip_runtime.h>
#include <hip/hip_bf16.h>

#define NBLK 100
#define DIM 128
#define EVEC (NBLK * DIM)          // 12800 elements per accumulator array
#define SLICE (2 * EVEC + NBLK)    // 25700 floats per slice
#define EPSV 1e-8f
#define SSCALE 4194304.0f          // 2^22 fixed-point scale for sums
#define NSCALE 16777216.0f         // 2^24 fixed-point scale for unit-vector sums
#define INV_SSCALE (1.0f / SSCALE)
#define INV_NSCALE (1.0f / NSCALE)
#define PPART 8                    // first-stage reduction fan-in

// ---------------------------------------------------------------------------
// Kernel 1: one pass over z. 16 lanes per point (float8 = 2x float4 loads),
// 4 points per wave iteration. Norm via 4-step intra-quarter shuffle reduce.
// Accumulation into per-WG LDS in int32 fixed point: atomicAdd(int*) is
// native ds_add_u32 (float atomicAdd on LDS compiles to a CAS loop -> R1's
// 26k-cycle/iter serialization). Dim permutation p(d)=64h + r + 16(k&1) +
// 32(k>>1), with k-parity XORed by quarter parity so each ds_add covers all
// 32 banks 2-way (free). Downstream dots/norms are permutation-invariant.
// ---------------------------------------------------------------------------
__global__ __launch_bounds__(1024) void rbc_accum(
    const float4* __restrict__ z4, const int* __restrict__ ids,
    float* __restrict__ ws, int N, int nwaves) {
  __shared__ int lsum[EVEC];
  __shared__ int lnsum[EVEC];
  __shared__ int lcnt[NBLK];
  const int tid = threadIdx.x;
  for (int e = tid; e < EVEC; e += 1024) { lsum[e] = 0; lnsum[e] = 0; }
  if (tid < NBLK) lcnt[tid] = 0;
  __syncthreads();

  const int lane = tid & 63;
  const int q  = lane >> 4;   // quarter (which of 4 points)
  const int r  = lane & 15;   // lane within quarter
  const int qp = q & 1;       // quarter parity for bank spreading
  const int w = blockIdx.x * (blockDim.x >> 6) + (tid >> 6);
  const int ngroups = N >> 2; // groups of 4 points

#define RBC_POINT_BODY(A0, A1, BB)                                           \
  {                                                                          \
    float sq = A0.x * A0.x + A0.y * A0.y + A0.z * A0.z + A0.w * A0.w +       \
               A1.x * A1.x + A1.y * A1.y + A1.z * A1.z + A1.w * A1.w;        \
    _Pragma("unroll")                                                        \
    for (int m = 1; m < 16; m <<= 1) sq += __shfl_xor(sq, m);                \
    const float rn = 1.0f / fmaxf(sqrtf(sq), EPSV);                          \
    const float v0[4] = {A0.x, A0.y, A0.z, A0.w};                            \
    const float v1[4] = {A1.x, A1.y, A1.z, A1.w};                            \
    const int base = BB * DIM;                                               \
    _Pragma("unroll")                                                        \
    for (int s = 0; s < 4; ++s) {                                            \
      const float x0 = qp ? v0[s ^ 1] : v0[s];                               \
      const float x1 = qp ? v1[s ^ 1] : v1[s];                               \
      const int p0 = base + r + ((((s & 1) ^ qp)) << 4) + ((s >> 1) << 5);   \
      atomicAdd(&lsum[p0], __float2int_rn(x0 * SSCALE));                     \
      atomicAdd(&lnsum[p0], __float2int_rn(x0 * rn * NSCALE));               \
      atomicAdd(&lsum[p0 + 64], __float2int_rn(x1 * SSCALE));                \
      atomicAdd(&lnsum[p0 + 64], __float2int_rn(x1 * rn * NSCALE));          \
    }                                                                        \
    if (r == 0) atomicAdd(&lcnt[BB], 1);                                     \
  }

  int j = w;
  for (; j + nwaves < ngroups; j += (nwaves << 1)) {
    const int jB = j + nwaves;
    const int iA = (j << 2) + q;
    const int iB = (jB << 2) + q;
    const float4* zpA = z4 + ((size_t)iA << 5);
    const float4* zpB = z4 + ((size_t)iB << 5);
    // issue all global loads before any LDS traffic
    const float4 a0 = zpA[r];
    const float4 a1 = zpA[r + 16];
    const float4 b0 = zpB[r];
    const float4 b1 = zpB[r + 16];
    const int bA = ids[iA];
    const int bB = ids[iB];
    RBC_POINT_BODY(a0, a1, bA);
    RBC_POINT_BODY(b0, b1, bB);
  }
  if (j < ngroups) {
    const int iA = (j << 2) + q;
    const float4* zpA = z4 + ((size_t)iA << 5);
    const float4 a0 = zpA[r];
    const float4 a1 = zpA[r + 16];
    const int bA = ids[iA];
    RBC_POINT_BODY(a0, a1, bA);
  }
  // tail points (N not multiple of 4) handled by block 0, wave 0
  if (blockIdx.x == 0 && (tid >> 6) == 0 && (N & 3)) {
    const int i = (ngroups << 2) + q;
    if (q < (N & 3)) {
      const float4* zp = z4 + ((size_t)i << 5);
      const float4 a0 = zp[r];
      const float4 a1 = zp[r + 16];
      const int b = ids[i];
      RBC_POINT_BODY(a0, a1, b);
    }
  }
#undef RBC_POINT_BODY
  __syncthreads();

  // non-atomic flush of this WG's private slice, converted back to float
  float* slice = ws + (size_t)blockIdx.x * SLICE;
  for (int e = tid; e < EVEC; e += 1024) {
    slice[e] = (float)lsum[e] * INV_SSCALE;
    slice[EVEC + e] = (float)lnsum[e] * INV_NSCALE;
  }
  if (tid < NBLK) slice[2 * EVEC + tid] = (float)lcnt[tid];
}

// ---------------------------------------------------------------------------
// Kernel 2: reduce G slices -> PPART partial slices (parallel over parts).
// ---------------------------------------------------------------------------
__global__ void rbc_reduce1(const float* __restrict__ ws,
                            float* __restrict__ part, int G, int GP) {
  const int e = blockIdx.x * 256 + threadIdx.x;
  if (e >= SLICE) return;
  const int p = blockIdx.y;
  float s = 0.f;
  const int g0 = p * GP;
  const int g1 = (g0 + GP < G) ? (g0 + GP) : G;
  for (int g = g0; g < g1; ++g) s += ws[(size_t)g * SLICE + e];
  part[(size_t)p * SLICE + e] = s;
}

// ---------------------------------------------------------------------------
// Kernel 3: fold PPART partials, per-block mean cosine, final scalar.
// One wave per block (16 waves); no FP atomics (per-block LDS + shuffle).
// ---------------------------------------------------------------------------
__global__ __launch_bounds__(1024) void rbc_final(const float* __restrict__ part,
                                                  float* __restrict__ out) {
  __shared__ float mres[NBLK];
  __shared__ float vld[NBLK];
  const int tid = threadIdx.x;
  const int wave = tid >> 6, lane = tid & 63;
  for (int b = wave; b < NBLK; b += 16) {
    float s0 = 0.f, s1 = 0.f, n0 = 0.f, n1 = 0.f, cnt = 0.f;
#pragma unroll
    for (int p = 0; p < PPART; ++p) {
      const float* f = part + (size_t)p * SLICE;
      s0 += f[b * DIM + lane];
      s1 += f[b * DIM + 64 + lane];
      n0 += f[EVEC + b * DIM + lane];
      n1 += f[EVEC + b * DIM + 64 + lane];
      cnt += f[2 * EVEC + b];   // same value in all lanes (broadcast load)
    }
    float S2 = s0 * s0 + s1 * s1;   // ||sums||^2
    float ND = n0 * s0 + n1 * s1;   // nsums . sums
#pragma unroll
    for (int m = 1; m < 64; m <<= 1) {
      S2 += __shfl_xor(S2, m);
      ND += __shfl_xor(ND, m);
    }
    if (lane == 0) {
      const float cnt1 = fmaxf(cnt, 1.0f);
      const float cn = fmaxf(sqrtf(S2) / cnt1, EPSV);     // ||center|| clamped
      const float mean_cos = ND / (cnt1 * cnt1 * cn);
      const bool valid = cnt > 1.0f;
      mres[b] = valid ? (1.0f - mean_cos) : 0.f;
      vld[b] = valid ? 1.0f : 0.f;
    }
  }
  __syncthreads();
  if (tid < 64) {
    float t = (tid < NBLK ? mres[tid] : 0.f) +
              (tid + 64 < NBLK ? mres[tid + 64] : 0.f);
    float c = (tid < NBLK ? vld[tid] : 0.f) +
              (tid + 64 < NBLK ? vld[tid + 64] : 0.f);
#pragma unroll
    for (int m = 1; m < 64; m <<= 1) {
      t += __shfl_xor(t, m);
      c += __shfl_xor(c, m);
    }
    if (tid == 0) out[0] = t / fmaxf(c, 1.0f);
  }
}

extern "C" void kernel_launch(void* const* d_in, const int* in_sizes, int n_in,
                              void* d_out, int out_size, void* d_ws, size_t ws_size,
                              hipStream_t stream) {
  const float* z = (const float*)d_in[0];
  const int* ids = (const int*)d_in[1];
  const int N = in_sizes[1];
  float* out = (float*)d_out;
  float* ws = (float*)d_ws;

  // need G + PPART slices in workspace
  size_t cap = ws_size / (sizeof(float) * (size_t)SLICE);
  int G = 256;
  if (cap < (size_t)(G + PPART)) {
    G = (int)cap - PPART;
    if (G < 1) G = 1;
  }
  const int nwaves = G * (1024 / 64);
  const int GP = (G + PPART - 1) / PPART;

  rbc_accum<<<G, 1024, 0, stream>>>((const float4*)z, ids, ws, N, nwaves);

  float* part = ws + (size_t)G * SLICE;
  dim3 rgrid((SLICE + 255) / 256, PPART);
  rbc_reduce1<<<rgrid, 256, 0, stream>>>(ws, part, G, GP);
  rbc_final<<<1, 1024, 0, stream>>>(part, out);
}